// Round 5
// baseline (144.434 us; speedup 1.0000x reference)
//
#include <hip/hip_runtime.h>
#include <hip/hip_fp16.h>

// GNNDecoder: out = relu((einsum("nk,nkl->nl", s, z[batch])) @ W1 + b1) @ W2 + b2
// N=100000, B=256, K=32, LATENT=64, HIDDEN=256, OUT=32. fp32 in/out.
//
// R4 post-mortem: 43KB LDS -> 3 blocks/CU (Occ 26%), f16 "+8" pad gave row
// strides = 4 dwords (mod 32) -> 1.4M bank-conflict cycles, 64 scalar
// ds_write_u16 transpose, 3 barriers: latency-bound at 71us with all pipes
// <10%. R5: each WAVE owns 16 nodes end-to-end -> zero __syncthreads (same-
// wave DS ops are in-order). Stage A computes D=W1^T(A-op) x lat(B-op) =
// h^T, so node stays in lane&15 and the stage-B A-fragment transpose packs
// r=0..3 into ONE ds_write_b64. All LDS in fragment-native [frag][lane][8]
// layout -> every b128 access lane-linear, conflict-free. LDS 25.4KB,
// launch_bounds(256,6) -> 6 blocks/CU (75% occ), grid fits ~1 generation.
// Verified frag maps (R4 passed on HW): A[m=lane&15][k=quad*8+j],
// B[k=quad*8+j][n=lane&15], C/D col=lane&15 row=quad*4+reg.

using f16   = _Float16;
using f16x4 = __attribute__((ext_vector_type(4))) _Float16;
using f16x8 = __attribute__((ext_vector_type(8))) _Float16;
using f32x4 = __attribute__((ext_vector_type(4))) float;

constexpr int NN     = 100000;
constexpr int KK     = 32;
constexpr int LATENT = 64;
constexpr int HIDDEN = 256;
constexpr int OUTD   = 32;

constexpr int NPB   = 64;    // nodes per block (16 per wave)
constexpr int BLOCK = 256;   // 4 waves

// ws layout (f16): W1 A-frags [g=nt*2+ks][64 lane][8]  = 16384 f16
//                  W2 B-frags [g=nt2*8+ks][64 lane][8] =  8192 f16
constexpr int W2F_OFF = 16384;

__global__ void convert_weights(const float* __restrict__ W1,
                                const float* __restrict__ W2,
                                f16* __restrict__ wsf) {
    const int tid = blockIdx.x * blockDim.x + threadIdx.x;
    if (tid < 16384) {
        const int j = tid & 7, lane = (tid >> 3) & 63, g = tid >> 9;
        const int ks = g & 1, nt = g >> 1;
        const int k = ks * 32 + (lane >> 4) * 8 + j;   // latent
        const int c = nt * 16 + (lane & 15);           // hidden
        wsf[tid] = (f16)W1[k * HIDDEN + c];
    } else if (tid < 16384 + 8192) {
        const int tid2 = tid - 16384;
        const int j = tid2 & 7, lane = (tid2 >> 3) & 63, g = tid2 >> 9;
        const int ks = g & 7, nt2 = g >> 3;
        const int k = ks * 32 + (lane >> 4) * 8 + j;   // hidden
        const int c = nt2 * 16 + (lane & 15);          // out
        wsf[W2F_OFF + tid2] = (f16)W2[k * OUTD + c];
    }
}

__global__ __launch_bounds__(BLOCK, 6)
void gnn_decoder(const float* __restrict__ z,      // [B, K, LATENT]
                 const float* __restrict__ s,      // [N, K]
                 const int*   __restrict__ batch,  // [N]
                 const f16*   __restrict__ wsf,    // swizzled f16 weights
                 const float* __restrict__ b1,     // [HIDDEN]
                 const float* __restrict__ b2,     // [OUT]
                 float*       __restrict__ out)    // [N, OUT]
{
    // All per-wave regions; no cross-wave sharing -> no __syncthreads.
    __shared__ f16   latf[4][2][64][8];     // 8 KB: lat B-frags per wave
    __shared__ f16   hcf[4][2][64][8];      // 8 KB: relu(h) A-frags, dbuf
    __shared__ float s_tile[4][16][36];     // 9.2 KB: stride 36 dw (16B-mult,
                                            // read bank (4n+k)%32 = 2-way free)

    const int t    = threadIdx.x;
    const int w    = t >> 6;                // wave 0..3
    const int lane = t & 63;
    const int lrow = lane & 15;
    const int quad = lane >> 4;
    const int base_row = blockIdx.x * NPB + w * 16;   // this wave's first node

    // ---- phase 0a: stage s rows (wave-local) + batch (register) ------------
    {
        const float* s_src = s + (size_t)base_row * KK;
        #pragma unroll
        for (int rep = 0; rep < 2; ++rep) {
            const int i4 = rep * 64 + lane;           // float4 idx 0..127
            const int n = i4 >> 3, k4 = (i4 & 7) * 4;
            float4 v = {0.f, 0.f, 0.f, 0.f};
            if (base_row + n < NN) v = *(const float4*)(s_src + n * KK + k4);
            *(float4*)&s_tile[w][n][k4] = v;          // 16B-aligned rows
        }
    }
    int bv = 0;
    if (lane < 16 && base_row + lane < NN) bv = batch[base_row + lane];
    __builtin_amdgcn_wave_barrier();

    // ---- phase 0b: lat[n][l] = sum_k s[n][k]*z[b][k][l] -> latf B-frags ----
    {
        const int n_local = lane >> 2;      // node 0..15 (this wave)
        const int lc      = lane & 3;       // latent chunk of 16
        const int b       = __shfl(bv, n_local);
        const float* zb = z + (size_t)b * (KK * LATENT) + lc * 16;

        float acc[16];
        #pragma unroll
        for (int x = 0; x < 16; ++x) acc[x] = 0.f;

        #pragma unroll 4
        for (int k = 0; k < KK; ++k) {
            const float sk = s_tile[w][n_local][k];
            const float4* zp = (const float4*)(zb + k * LATENT);
            const float4 z0 = zp[0], z1 = zp[1], z2 = zp[2], z3 = zp[3];
            acc[0]  += sk * z0.x;  acc[1]  += sk * z0.y;
            acc[2]  += sk * z0.z;  acc[3]  += sk * z0.w;
            acc[4]  += sk * z1.x;  acc[5]  += sk * z1.y;
            acc[6]  += sk * z1.z;  acc[7]  += sk * z1.w;
            acc[8]  += sk * z2.x;  acc[9]  += sk * z2.y;
            acc[10] += sk * z2.z;  acc[11] += sk * z2.w;
            acc[12] += sk * z3.x;  acc[13] += sk * z3.y;
            acc[14] += sk * z3.z;  acc[15] += sk * z3.w;
        }
        // latf[w][ks][quad*16 + node][j] = lat[node][ks*32+quad*8+j]
        const int ks = lc >> 1, q0 = (lc & 1) * 2;
        f16x8 v0, v1;
        #pragma unroll
        for (int q = 0; q < 8; ++q) { v0[q] = (f16)acc[q]; v1[q] = (f16)acc[8 + q]; }
        *(f16x8*)&latf[w][ks][q0 * 16 + n_local][0]       = v0;  // b128, balanced
        *(f16x8*)&latf[w][ks][(q0 + 1) * 16 + n_local][0] = v1;
    }
    __builtin_amdgcn_wave_barrier();

    // ---- fused stages A+B, per 32-hidden group (zero barriers) -------------
    const f16x8*  W1f = (const f16x8*)wsf;               // [32][64] frags
    const f16x8*  W2f = (const f16x8*)(wsf + W2F_OFF);   // [16][64] frags
    const float4* b1v = (const float4*)b1;

    const f16x8 latB0 = *(const f16x8*)&latf[w][0][lane][0];  // lane-linear
    const f16x8 latB1 = *(const f16x8*)&latf[w][1][lane][0];

    f32x4 O0 = {0.f, 0.f, 0.f, 0.f};
    f32x4 O1 = {0.f, 0.f, 0.f, 0.f};

    #pragma unroll
    for (int ksH = 0; ksH < 8; ++ksH) {
        // stage A: D[hid][node] for hiddens ksH*32..+32 (2 tiles of 16)
        #pragma unroll
        for (int p = 0; p < 2; ++p) {
            const int ntA = ksH * 2 + p;
            f32x4 C = {0.f, 0.f, 0.f, 0.f};
            C = __builtin_amdgcn_mfma_f32_16x16x32_f16(
                    W1f[(ntA * 2 + 0) * 64 + lane], latB0, C, 0, 0, 0);
            C = __builtin_amdgcn_mfma_f32_16x16x32_f16(
                    W1f[(ntA * 2 + 1) * 64 + lane], latB1, C, 0, 0, 0);
            // D: col=node=lrow, row=hid=ntA*16+quad*4+r. relu+b1, pack 4 f16
            const float4 bq = b1v[ntA * 4 + quad];
            f16x4 hv;
            hv[0] = (f16)fmaxf(C[0] + bq.x, 0.f);
            hv[1] = (f16)fmaxf(C[1] + bq.y, 0.f);
            hv[2] = (f16)fmaxf(C[2] + bq.z, 0.f);
            hv[3] = (f16)fmaxf(C[3] + bq.w, 0.f);
            // A-frag slot for (node=lrow, hid_local=p*16+quad*4+r):
            // quad2 = p*2 + quad/2, j0 = (quad&1)*4 -> one b64, bank-balanced
            *(f16x4*)&hcf[w][ksH & 1][(p * 2 + (quad >> 1)) * 16 + lrow][(quad & 1) * 4] = hv;
        }
        __builtin_amdgcn_wave_barrier();
        // stage B: O[node][out] += relu(h)[ksH block] @ W2
        const f16x8 Ah = *(const f16x8*)&hcf[w][ksH & 1][lane][0];  // lane-linear
        O0 = __builtin_amdgcn_mfma_f32_16x16x32_f16(Ah, W2f[(0 * 8 + ksH) * 64 + lane], O0, 0, 0, 0);
        O1 = __builtin_amdgcn_mfma_f32_16x16x32_f16(Ah, W2f[(1 * 8 + ksH) * 64 + lane], O1, 0, 0, 0);
    }

    // ---- epilogue: D2 col=out=lrow, row=node=quad*4+r; +b2, store ----------
    {
        const float b2a = b2[lrow];
        const float b2b = b2[16 + lrow];
        #pragma unroll
        for (int r = 0; r < 4; ++r) {
            const int gn = base_row + quad * 4 + r;
            if (gn < NN) {
                out[(size_t)gn * OUTD + lrow]      = O0[r] + b2a;   // 64B/quad-row
                out[(size_t)gn * OUTD + 16 + lrow] = O1[r] + b2b;
            }
        }
    }
}

extern "C" void kernel_launch(void* const* d_in, const int* in_sizes, int n_in,
                              void* d_out, int out_size, void* d_ws, size_t ws_size,
                              hipStream_t stream) {
    const float* z     = (const float*)d_in[0];
    const float* s     = (const float*)d_in[1];
    const int*   batch = (const int*)d_in[2];
    const float* W1    = (const float*)d_in[3];
    const float* b1    = (const float*)d_in[4];
    const float* W2    = (const float*)d_in[5];
    const float* b2    = (const float*)d_in[6];
    float* out = (float*)d_out;
    f16* wsf = (f16*)d_ws;   // needs 48 KB

    convert_weights<<<96, 256, 0, stream>>>(W1, W2, wsf);

    const int grid = (NN + NPB - 1) / NPB;  // 1563
    gnn_decoder<<<grid, BLOCK, 0, stream>>>(z, s, batch, wsf, b1, b2, out);
}